// Round 1
// baseline (1075.806 us; speedup 1.0000x reference)
//
#include <hip/hip_runtime.h>

typedef __attribute__((ext_vector_type(8))) short short8;
typedef __attribute__((ext_vector_type(4))) float float4v;

#define NDIM 512
#define NN (NDIM*NDIM)
#define CD 128

__device__ __forceinline__ unsigned short f2b(float f) {
  union { float f; unsigned u; } v; v.f = f;
  unsigned r = v.u + 0x7FFFu + ((v.u >> 16) & 1u);
  return (unsigned short)(r >> 16);
}
__device__ __forceinline__ float b2f(unsigned short h) {
  union { unsigned u; float f; } v; v.u = ((unsigned)h) << 16; return v.f;
}
__device__ __forceinline__ float sigmoidf_(float x) { return 1.f / (1.f + __expf(-x)); }

__device__ __forceinline__ float4v mfma16(short8 a, short8 b, float4v c) {
  return __builtin_amdgcn_mfma_f32_16x16x32_bf16(a, b, c, 0, 0, 0);
}

// Stage a 128x128 f32 weight (layout [k][n]) into LDS as bf16 transposed [n][k],
// row stride 136 (16B-aligned rows, bank-uniform fragment reads).
// Reads are column-ish (L1-resident after first touch: 64KB weight), writes are
// k-parallel across lanes -> ~2-way LDS write conflicts only.
#define STAGE_WF(WPTR) do {                                               \
  _Pragma("unroll 16")                                                    \
  for (int i_ = 0; i_ < 64; ++i_) {                                       \
    int v_ = i_*256 + t;                                                  \
    int n_ = v_ >> 7, k_ = v_ & 127;                                      \
    wbuf[n_*136 + k_] = (short)f2b(WPTR[(size_t)k_*CD + n_]);             \
  }                                                                       \
} while(0)

// 64 output rows (wave w owns rows w*16..w*16+15), 128 output cols, K=128.
// af[4] from zln-style LDS (stride 136); B operand from wbuf [n][k].
#define MFMA_PASS(ACC) do {                                               \
  _Pragma("unroll")                                                       \
  for (int cf_ = 0; cf_ < 8; ++cf_) ACC[cf_] = (float4v){0.f,0.f,0.f,0.f};\
  _Pragma("unroll")                                                       \
  for (int ks_ = 0; ks_ < 4; ++ks_) {                                     \
    _Pragma("unroll")                                                     \
    for (int cf_ = 0; cf_ < 8; ++cf_) {                                   \
      short8 bf_ = *(const short8*)&wbuf[(cf_*16 + lr)*136 + ks_*32 + lg*8]; \
      ACC[cf_] = mfma16(af[ks_], bf_, ACC[cf_]);                          \
    }                                                                     \
  }                                                                       \
} while(0)

// write transposed bf16 tile: ast LDS [128 c][72 stride] -> DST[c][r0..r0+64)
#define STORE_T(DST) do {                                                 \
  _Pragma("unroll")                                                       \
  for (int it_ = 0; it_ < 4; ++it_) {                                     \
    int v_ = it_*256 + t; int c_ = v_ >> 3; int ro_ = (v_ & 7) * 8;       \
    *(short8*)(DST + (size_t)c_*NN + r0 + ro_) =                          \
        *(const short8*)&sA[c_*72 + ro_];                                 \
  }                                                                       \
} while(0)

// ---------------- kernel 1: LN(z) + 5 projections + gating ----------------
__global__ __launch_bounds__(256) void kProj(
    const float* __restrict__ z, const float* __restrict__ mask,
    const float* __restrict__ w_a_p, const float* __restrict__ b_a_p,
    const float* __restrict__ w_a_g, const float* __restrict__ b_a_g,
    const float* __restrict__ w_b_p, const float* __restrict__ b_b_p,
    const float* __restrict__ w_b_g, const float* __restrict__ b_b_g,
    const float* __restrict__ w_g,  const float* __restrict__ b_g,
    const float* __restrict__ ln_s, const float* __restrict__ ln_b,
    short* __restrict__ a_t, short* __restrict__ b_t, short* __restrict__ g_out)
{
  __shared__ short sA[9216];        // zln[64][136] | ast[128][72] | gst[64][136]
  __shared__ short wbuf[128*136];

  const int t = threadIdx.x;
  const int r0 = blockIdx.x * 64;
  const int w = t >> 6, l = t & 63, lr = l & 15, lg = l >> 4;

  // ---- layernorm of 64 z rows (4 threads per row, 32 f32 each) ----
  {
    const int r = t >> 2, q = t & 3;
    const float* zp = z + (size_t)(r0 + r) * CD + q * 32;
    float x[32];
#pragma unroll
    for (int i = 0; i < 8; ++i) {
      float4v v = *(const float4v*)(zp + i * 4);
#pragma unroll
      for (int e = 0; e < 4; ++e) x[i*4+e] = v[e];
    }
    float s = 0.f;
#pragma unroll
    for (int i = 0; i < 32; ++i) s += x[i];
    s += __shfl_xor(s, 1, 64);
    s += __shfl_xor(s, 2, 64);
    const float mu = s * (1.f/128.f);
    float vs = 0.f;
#pragma unroll
    for (int i = 0; i < 32; ++i) { float d = x[i]-mu; vs += d*d; }
    vs += __shfl_xor(vs, 1, 64);
    vs += __shfl_xor(vs, 2, 64);
    const float rstd = rsqrtf(vs * (1.f/128.f) + 1e-5f);
#pragma unroll
    for (int i = 0; i < 32; ++i) {
      int c = q*32 + i;
      float y = (x[i]-mu)*rstd*ln_s[c] + ln_b[c];
      sA[r*136 + c] = (short)f2b(y);
    }
  }
  STAGE_WF(w_a_p);
  __syncthreads();                                  // s1: zln + wbuf(a_p)

  short8 af[4];
#pragma unroll
  for (int ks = 0; ks < 4; ++ks)
    af[ks] = *(const short8*)&sA[(w*16 + lr)*136 + ks*32 + lg*8];
  float mrow[4];
#pragma unroll
  for (int jj = 0; jj < 4; ++jj) mrow[jj] = mask[r0 + w*16 + lg*4 + jj];

  float4v accP[8], accG[8];
  MFMA_PASS(accP);                                  // a_p
  __syncthreads();                                  // s2
  STAGE_WF(w_a_g);
  __syncthreads();                                  // s3
  MFMA_PASS(accG);                                  // a_g
  __syncthreads();                                  // s4
  STAGE_WF(w_b_p);
  {                                                 // a = sig(g)+bias stuff -> ast
    float bp[8], bg8[8];
#pragma unroll
    for (int cf = 0; cf < 8; ++cf) { bp[cf] = b_a_p[cf*16+lr]; bg8[cf] = b_a_g[cf*16+lr]; }
#pragma unroll
    for (int cf = 0; cf < 8; ++cf)
#pragma unroll
      for (int jj = 0; jj < 4; ++jj) {
        float av = sigmoidf_(accG[cf][jj] + bg8[cf]) * mrow[jj] * (accP[cf][jj] + bp[cf]);
        sA[(cf*16+lr)*72 + w*16 + lg*4 + jj] = (short)f2b(av);
      }
  }
  __syncthreads();                                  // s5: ast(a) + wbuf(b_p)
  STORE_T(a_t);
  MFMA_PASS(accP);                                  // b_p
  __syncthreads();                                  // s6
  STAGE_WF(w_b_g);
  __syncthreads();                                  // s7
  MFMA_PASS(accG);                                  // b_g
  __syncthreads();                                  // s8
  STAGE_WF(w_g);
  {                                                 // b values -> ast
    float bp[8], bg8[8];
#pragma unroll
    for (int cf = 0; cf < 8; ++cf) { bp[cf] = b_b_p[cf*16+lr]; bg8[cf] = b_b_g[cf*16+lr]; }
#pragma unroll
    for (int cf = 0; cf < 8; ++cf)
#pragma unroll
      for (int jj = 0; jj < 4; ++jj) {
        float bv = sigmoidf_(accG[cf][jj] + bg8[cf]) * mrow[jj] * (accP[cf][jj] + bp[cf]);
        sA[(cf*16+lr)*72 + w*16 + lg*4 + jj] = (short)f2b(bv);
      }
  }
  __syncthreads();                                  // s9: ast(b) + wbuf(w_g)
  STORE_T(b_t);
  MFMA_PASS(accP);                                  // w_g projection
  __syncthreads();                                  // s10: ast reads done
  {                                                 // g = sigmoid(.) -> gst natural [r][c]
    float bgv[8];
#pragma unroll
    for (int cf = 0; cf < 8; ++cf) bgv[cf] = b_g[cf*16+lr];
#pragma unroll
    for (int cf = 0; cf < 8; ++cf)
#pragma unroll
      for (int jj = 0; jj < 4; ++jj)
        sA[(w*16+lg*4+jj)*136 + cf*16+lr] = (short)f2b(sigmoidf_(accP[cf][jj] + bgv[cf]));
  }
  __syncthreads();                                  // s11
#pragma unroll
  for (int it = 0; it < 4; ++it) {
    int v = it*256 + t; int rr = v >> 4; int co = (v & 15) * 8;
    *(short8*)(g_out + (size_t)(r0+rr)*CD + co) = *(const short8*)&sA[rr*136 + co];
  }
}

// ---------------- kernel 2: per-channel einsum GEMM X_c = A_c * B_c^T ----------------
__global__ __launch_bounds__(256) void kEinsum(const short* __restrict__ a_t,
                                               const short* __restrict__ b_t,
                                               short* __restrict__ x_t)
{
  __shared__ short Asb[128*32];
  __shared__ short Bsb[128*32];
  const int t = threadIdx.x;
  const int c = blockIdx.y;
  const int i0 = (blockIdx.x >> 2) * 128;
  const int j0 = (blockIdx.x & 3) * 128;
  const size_t abase = (size_t)c * NN;
  const int w = t >> 6, l = t & 63, lr = l & 15, lg = l >> 4;
  const int wr = w >> 1, wc = w & 1;

  float4v acc[4][4];
#pragma unroll
  for (int m = 0; m < 4; ++m)
#pragma unroll
    for (int n = 0; n < 4; ++n) acc[m][n] = (float4v){0.f,0.f,0.f,0.f};

  for (int it = 0; it < 16; ++it) {
    const int k0 = it * 32;
    short8 va[2], vb[2];
#pragma unroll
    for (int i = 0; i < 2; ++i) {                 // reg-stage tile (it)
      int flat = i*256 + t; int row = flat >> 2; int ko = (flat & 3) * 8;
      va[i] = *(const short8*)(a_t + abase + (size_t)(i0 + row)*NDIM + k0 + ko);
      vb[i] = *(const short8*)(b_t + abase + (size_t)(j0 + row)*NDIM + k0 + ko);
    }
    __syncthreads();                              // prev-iter LDS reads done
#pragma unroll
    for (int i = 0; i < 2; ++i) {
      int flat = i*256 + t;
      *(short8*)(Asb + flat*8) = va[i];
      *(short8*)(Bsb + flat*8) = vb[i];
    }
    __syncthreads();                              // LDS ready
    short8 afr[4], bfr[4];
#pragma unroll
    for (int m = 0; m < 4; ++m)
      afr[m] = *(const short8*)(Asb + (wr*64 + m*16 + lr)*32 + lg*8);
#pragma unroll
    for (int n = 0; n < 4; ++n)
      bfr[n] = *(const short8*)(Bsb + (wc*64 + n*16 + lr)*32 + lg*8);
#pragma unroll
    for (int m = 0; m < 4; ++m)
#pragma unroll
      for (int n = 0; n < 4; ++n)
        acc[m][n] = mfma16(afr[m], bfr[n], acc[m][n]);
  }
  // epilogue: x_t[c][i][j] bf16
#pragma unroll
  for (int m = 0; m < 4; ++m)
#pragma unroll
    for (int n = 0; n < 4; ++n)
#pragma unroll
      for (int jj = 0; jj < 4; ++jj) {
        int row = i0 + wr*64 + m*16 + lg*4 + jj;
        int col = j0 + wc*64 + n*16 + lr;
        x_t[abase + (size_t)row*NDIM + col] = (short)f2b(acc[m][n][jj]);
      }
}

// ---------------- kernel 3: LN(x) + x@w_z + b_z, * gate ----------------
__global__ __launch_bounds__(256) void kOut(
    const short* __restrict__ x_t, const short* __restrict__ g_in,
    const float* __restrict__ w_z, const float* __restrict__ b_z,
    const float* __restrict__ ln_s, const float* __restrict__ ln_b,
    float* __restrict__ out)
{
  __shared__ short sX[10240];       // xs[128][80] | xln[64][136]
  __shared__ short wbuf[128*136];
  const int t = threadIdx.x;
  const int r0 = blockIdx.x * 64;
  const int w = t >> 6, l = t & 63, lr = l & 15, lg = l >> 4;

  STAGE_WF(w_z);
#pragma unroll
  for (int it = 0; it < 4; ++it) {                // gather x_t columns -> xs
    int v = it*256 + t; int cc = v >> 3; int ro = (v & 7) * 8;
    *(short8*)&sX[cc*80 + ro] = *(const short8*)(x_t + (size_t)cc*NN + r0 + ro);
  }
  __syncthreads();                                // s1
  const int r = t >> 2, q = t & 3;
  float x[32];
#pragma unroll
  for (int i = 0; i < 32; ++i) x[i] = b2f((unsigned short)sX[(q*32+i)*80 + r]);
  float s = 0.f;
#pragma unroll
  for (int i = 0; i < 32; ++i) s += x[i];
  s += __shfl_xor(s, 1, 64);
  s += __shfl_xor(s, 2, 64);
  const float mu = s * (1.f/128.f);
  float vs = 0.f;
#pragma unroll
  for (int i = 0; i < 32; ++i) { float d = x[i]-mu; vs += d*d; }
  vs += __shfl_xor(vs, 1, 64);
  vs += __shfl_xor(vs, 2, 64);
  const float rstd = rsqrtf(vs * (1.f/128.f) + 1e-5f);
  __syncthreads();                                // s2: xs reads complete
#pragma unroll
  for (int i = 0; i < 32; ++i) {
    int c = q*32 + i;
    float y = (x[i]-mu)*rstd*ln_s[c] + ln_b[c];
    sX[r*136 + c] = (short)f2b(y);
  }
  __syncthreads();                                // s3: xln + wbuf ready
  short8 af[4];
#pragma unroll
  for (int ks = 0; ks < 4; ++ks)
    af[ks] = *(const short8*)&sX[(w*16 + lr)*136 + ks*32 + lg*8];
  float4v acc[8];
  MFMA_PASS(acc);
  float bz[8];
#pragma unroll
  for (int cf = 0; cf < 8; ++cf) bz[cf] = b_z[cf*16 + lr];
#pragma unroll
  for (int cf = 0; cf < 8; ++cf)
#pragma unroll
    for (int jj = 0; jj < 4; ++jj) {
      int rl = w*16 + lg*4 + jj;
      size_t off = (size_t)(r0 + rl)*CD + cf*16 + lr;
      out[off] = (acc[cf][jj] + bz[cf]) * b2f((unsigned short)g_in[off]);
    }
}

extern "C" void kernel_launch(void* const* d_in, const int* in_sizes, int n_in,
                              void* d_out, int out_size, void* d_ws, size_t ws_size,
                              hipStream_t stream) {
  (void)in_sizes; (void)n_in; (void)out_size; (void)ws_size;
  const float* z     = (const float*)d_in[0];
  const float* mask  = (const float*)d_in[1];
  const float* w_a_p = (const float*)d_in[2];
  const float* b_a_p = (const float*)d_in[3];
  const float* w_a_g = (const float*)d_in[4];
  const float* b_a_g = (const float*)d_in[5];
  const float* w_b_p = (const float*)d_in[6];
  const float* b_b_p = (const float*)d_in[7];
  const float* w_b_g = (const float*)d_in[8];
  const float* b_b_g = (const float*)d_in[9];
  const float* w_g   = (const float*)d_in[10];
  const float* b_g   = (const float*)d_in[11];
  const float* w_z   = (const float*)d_in[12];
  const float* b_z   = (const float*)d_in[13];
  const float* ln_i_s = (const float*)d_in[14];
  const float* ln_i_b = (const float*)d_in[15];
  const float* ln_o_s = (const float*)d_in[16];
  const float* ln_o_b = (const float*)d_in[17];

  short* a_t = (short*)d_ws;                       // 64 MiB each, 256 MiB total
  short* b_t = a_t + (size_t)CD*NN;
  short* g_s = b_t + (size_t)CD*NN;
  short* x_t = g_s + (size_t)CD*NN;

  hipLaunchKernelGGL(kProj, dim3(NN/64), dim3(256), 0, stream,
                     z, mask, w_a_p, b_a_p, w_a_g, b_a_g, w_b_p, b_b_p,
                     w_b_g, b_b_g, w_g, b_g, ln_i_s, ln_i_b, a_t, b_t, g_s);
  hipLaunchKernelGGL(kEinsum, dim3(16, 128), dim3(256), 0, stream, a_t, b_t, x_t);
  hipLaunchKernelGGL(kOut, dim3(NN/64), dim3(256), 0, stream,
                     x_t, g_s, w_z, b_z, ln_o_s, ln_o_b, (float*)d_out);
}

// Round 2
// 562.047 us; speedup vs baseline: 1.9141x; 1.9141x over previous
//
#include <hip/hip_runtime.h>

typedef __attribute__((ext_vector_type(8))) short short8;
typedef __attribute__((ext_vector_type(4))) float float4v;

#define NDIM 512
#define NN (NDIM*NDIM)
#define CD 128

__device__ __forceinline__ unsigned short f2b(float f) {
  union { float f; unsigned u; } v; v.f = f;
  unsigned r = v.u + 0x7FFFu + ((v.u >> 16) & 1u);
  return (unsigned short)(r >> 16);
}
__device__ __forceinline__ float b2f(unsigned short h) {
  union { unsigned u; float f; } v; v.u = ((unsigned)h) << 16; return v.f;
}
__device__ __forceinline__ float sigmoidf_(float x) { return 1.f / (1.f + __expf(-x)); }

__device__ __forceinline__ float4v mfma16(short8 a, short8 b, float4v c) {
  return __builtin_amdgcn_mfma_f32_16x16x32_bf16(a, b, c, 0, 0, 0);
}

__device__ __forceinline__ void gl_lds16(const short* g, short* l) {
  __builtin_amdgcn_global_load_lds(
      (const __attribute__((address_space(1))) unsigned int*)g,
      (__attribute__((address_space(3))) unsigned int*)l, 16, 0, 0);
}

// one MFMA pass: af[4] (zln rows) x weight WI from global bf16 wT [n][k]
#define PROJ_PASS(ACC, WI) do {                                           \
  _Pragma("unroll")                                                       \
  for (int cf_ = 0; cf_ < 8; ++cf_) {                                     \
    float4v a_ = {0.f,0.f,0.f,0.f};                                       \
    _Pragma("unroll")                                                     \
    for (int ks_ = 0; ks_ < 4; ++ks_) {                                   \
      short8 bf_ = *(const short8*)(wT + (WI)*16384 + (cf_*16+lr)*CD + ks_*32 + lg*8); \
      a_ = mfma16(af[ks_], bf_, a_);                                      \
    }                                                                     \
    ACC[cf_] = a_;                                                        \
  }                                                                       \
} while(0)

// write transposed bf16 tile: ast LDS [128 c][72 stride] -> DST[c][r0..r0+64)
#define STORE_T(DST) do {                                                 \
  _Pragma("unroll")                                                       \
  for (int it_ = 0; it_ < 4; ++it_) {                                     \
    int v_ = it_*256 + t; int c_ = v_ >> 3; int ro_ = (v_ & 7) * 8;       \
    *(short8*)(DST + (size_t)c_*NN + r0 + ro_) =                          \
        *(const short8*)&sA[c_*72 + ro_];                                 \
  }                                                                       \
} while(0)

// ---------------- kernel 0: weight prep f32 [k][n] -> bf16 [n][k] ----------------
__global__ __launch_bounds__(256) void kPrepW(
    const float* __restrict__ w0, const float* __restrict__ w1,
    const float* __restrict__ w2, const float* __restrict__ w3,
    const float* __restrict__ w4, short* __restrict__ wt)
{
  const int wi = blockIdx.y;
  const float* W = wi==0 ? w0 : wi==1 ? w1 : wi==2 ? w2 : wi==3 ? w3 : w4;
  const int e = blockIdx.x*256 + threadIdx.x;     // 0..16383
  const int n = e >> 7, k = e & 127;
  wt[wi*16384 + e] = (short)f2b(W[k*CD + n]);
}

// ---------------- kernel 1: LN(z) + 5 projections + gating ----------------
__global__ __launch_bounds__(256) void kProj(
    const float* __restrict__ z, const float* __restrict__ mask,
    const short* __restrict__ wT,
    const float* __restrict__ b_a_p, const float* __restrict__ b_a_g,
    const float* __restrict__ b_b_p, const float* __restrict__ b_b_g,
    const float* __restrict__ b_g,
    const float* __restrict__ ln_s, const float* __restrict__ ln_b,
    short* __restrict__ a_t, short* __restrict__ b_t, short* __restrict__ g_out)
{
  __shared__ short sA[9216];        // zln[64][136] -> ast[128][72] -> gst[64][136]
  const int t = threadIdx.x;
  const int r0 = blockIdx.x * 64;
  const int w = t >> 6, l = t & 63, lr = l & 15, lg = l >> 4;

  // ---- layernorm of 64 z rows (4 threads per row, 32 f32 each) ----
  {
    const int r = t >> 2, q = t & 3;
    const float* zp = z + (size_t)(r0 + r) * CD + q * 32;
    float x[32];
#pragma unroll
    for (int i = 0; i < 8; ++i) {
      float4v v = *(const float4v*)(zp + i * 4);
#pragma unroll
      for (int e = 0; e < 4; ++e) x[i*4+e] = v[e];
    }
    float s = 0.f;
#pragma unroll
    for (int i = 0; i < 32; ++i) s += x[i];
    s += __shfl_xor(s, 1, 64);
    s += __shfl_xor(s, 2, 64);
    const float mu = s * (1.f/128.f);
    float vs = 0.f;
#pragma unroll
    for (int i = 0; i < 32; ++i) { float d = x[i]-mu; vs += d*d; }
    vs += __shfl_xor(vs, 1, 64);
    vs += __shfl_xor(vs, 2, 64);
    const float rstd = rsqrtf(vs * (1.f/128.f) + 1e-5f);
#pragma unroll
    for (int i = 0; i < 32; ++i) {
      int c = q*32 + i;
      float y = (x[i]-mu)*rstd*ln_s[c] + ln_b[c];
      sA[r*136 + c] = (short)f2b(y);
    }
  }
  __syncthreads();                                  // s1: zln ready

  short8 af[4];
#pragma unroll
  for (int ks = 0; ks < 4; ++ks)
    af[ks] = *(const short8*)&sA[(w*16 + lr)*136 + ks*32 + lg*8];
  float mrow[4];
#pragma unroll
  for (int jj = 0; jj < 4; ++jj) mrow[jj] = mask[r0 + w*16 + lg*4 + jj];
  __syncthreads();                                  // s2: af loaded, sA reusable

  float4v accP[8], accG[8];
  PROJ_PASS(accP, 0);                               // a_p
  PROJ_PASS(accG, 1);                               // a_g
  {                                                 // a -> ast
    float bp[8], bg8[8];
#pragma unroll
    for (int cf = 0; cf < 8; ++cf) { bp[cf] = b_a_p[cf*16+lr]; bg8[cf] = b_a_g[cf*16+lr]; }
#pragma unroll
    for (int cf = 0; cf < 8; ++cf)
#pragma unroll
      for (int jj = 0; jj < 4; ++jj) {
        float av = sigmoidf_(accG[cf][jj] + bg8[cf]) * mrow[jj] * (accP[cf][jj] + bp[cf]);
        sA[(cf*16+lr)*72 + w*16 + lg*4 + jj] = (short)f2b(av);
      }
  }
  __syncthreads();                                  // s3: ast(a) ready
  STORE_T(a_t);
  PROJ_PASS(accP, 2);                               // b_p
  PROJ_PASS(accG, 3);                               // b_g
  __syncthreads();                                  // s4: STORE_T(a) LDS reads done
  {                                                 // b -> ast
    float bp[8], bg8[8];
#pragma unroll
    for (int cf = 0; cf < 8; ++cf) { bp[cf] = b_b_p[cf*16+lr]; bg8[cf] = b_b_g[cf*16+lr]; }
#pragma unroll
    for (int cf = 0; cf < 8; ++cf)
#pragma unroll
      for (int jj = 0; jj < 4; ++jj) {
        float bv = sigmoidf_(accG[cf][jj] + bg8[cf]) * mrow[jj] * (accP[cf][jj] + bp[cf]);
        sA[(cf*16+lr)*72 + w*16 + lg*4 + jj] = (short)f2b(bv);
      }
  }
  __syncthreads();                                  // s5: ast(b) ready
  STORE_T(b_t);
  PROJ_PASS(accP, 4);                               // w_g projection
  __syncthreads();                                  // s6: STORE_T(b) LDS reads done
  {                                                 // g = sigmoid(.) -> gst natural [r][c]
    float bgv[8];
#pragma unroll
    for (int cf = 0; cf < 8; ++cf) bgv[cf] = b_g[cf*16+lr];
#pragma unroll
    for (int cf = 0; cf < 8; ++cf)
#pragma unroll
      for (int jj = 0; jj < 4; ++jj)
        sA[(w*16+lg*4+jj)*136 + cf*16+lr] = (short)f2b(sigmoidf_(accP[cf][jj] + bgv[cf]));
  }
  __syncthreads();                                  // s7
#pragma unroll
  for (int it = 0; it < 4; ++it) {
    int v = it*256 + t; int rr = v >> 4; int co = (v & 15) * 8;
    *(short8*)(g_out + (size_t)(r0+rr)*CD + co) = *(const short8*)&sA[rr*136 + co];
  }
}

// ---------------- kernel 2: per-channel einsum GEMM X_c = A_c * B_c^T ----------------
__global__ __launch_bounds__(256) void kEinsum(const short* __restrict__ a_t,
                                               const short* __restrict__ b_t,
                                               short* __restrict__ x_t)
{
  __shared__ short Asb[128*32];
  __shared__ short Bsb[128*32];
  const int t = threadIdx.x;
  // XCD swizzle: all 16 tiles of one channel land on the same XCD (d % 8)
  const int d = blockIdx.x;
  const int c = (d & 7)*16 + (d >> 7);
  const int tile = (d >> 3) & 15;
  const int i0 = (tile >> 2) * 128;
  const int j0 = (tile & 3) * 128;
  const size_t abase = (size_t)c * NN;
  const int w = t >> 6, l = t & 63, lr = l & 15, lg = l >> 4;
  const int wr = w >> 1, wc = w & 1;

  // staging addresses: flat = half*256 + t ; row = flat>>2, ko = (flat&3)*8
  const int rowA0 = t >> 2, koA = (t & 3) * 8;
  const short* ga0 = a_t + abase + (size_t)(i0 + rowA0)*NDIM + koA;
  const short* ga1 = a_t + abase + (size_t)(i0 + 64 + rowA0)*NDIM + koA;
  const short* gb0 = b_t + abase + (size_t)(j0 + rowA0)*NDIM + koA;
  const short* gb1 = b_t + abase + (size_t)(j0 + 64 + rowA0)*NDIM + koA;
  short* la0 = Asb + t*8;
  short* la1 = Asb + (256 + t)*8;
  short* lb0 = Bsb + t*8;
  short* lb1 = Bsb + (256 + t)*8;

  float4v acc[4][4];
#pragma unroll
  for (int m = 0; m < 4; ++m)
#pragma unroll
    for (int n = 0; n < 4; ++n) acc[m][n] = (float4v){0.f,0.f,0.f,0.f};

  for (int it = 0; it < 16; ++it) {
    const int k0 = it * 32;
    __syncthreads();                              // prev-iter LDS reads done
    gl_lds16(ga0 + k0, la0);
    gl_lds16(ga1 + k0, la1);
    gl_lds16(gb0 + k0, lb0);
    gl_lds16(gb1 + k0, lb1);
    __syncthreads();                              // loads drained (vmcnt0 at barrier)
    short8 afr[4], bfr[4];
#pragma unroll
    for (int m = 0; m < 4; ++m)
      afr[m] = *(const short8*)(Asb + (wr*64 + m*16 + lr)*32 + lg*8);
#pragma unroll
    for (int n = 0; n < 4; ++n)
      bfr[n] = *(const short8*)(Bsb + (wc*64 + n*16 + lr)*32 + lg*8);
#pragma unroll
    for (int m = 0; m < 4; ++m)
#pragma unroll
      for (int n = 0; n < 4; ++n)
        acc[m][n] = mfma16(afr[m], bfr[n], acc[m][n]);
  }
  // epilogue: x_t[c][i][j] bf16
#pragma unroll
  for (int m = 0; m < 4; ++m)
#pragma unroll
    for (int n = 0; n < 4; ++n)
#pragma unroll
      for (int jj = 0; jj < 4; ++jj) {
        int row = i0 + wr*64 + m*16 + lg*4 + jj;
        int col = j0 + wc*64 + n*16 + lr;
        x_t[abase + (size_t)row*NDIM + col] = (short)f2b(acc[m][n][jj]);
      }
}

// ---------------- kernel 3: LN(x) + x@w_z + b_z, * gate ----------------
__global__ __launch_bounds__(256) void kOut(
    const short* __restrict__ x_t, const short* __restrict__ g_in,
    const float* __restrict__ w_z, const float* __restrict__ b_z,
    const float* __restrict__ ln_s, const float* __restrict__ ln_b,
    float* __restrict__ out)
{
  __shared__ short sX[10240];       // xs[128][80] -> xln[64][136]
  __shared__ short sG[64*132];      // gate tile, stride 132 (conflict-free reads)
  const int t = threadIdx.x;
  const int r0 = blockIdx.x * 64;
  const int w = t >> 6, l = t & 63, lr = l & 15, lg = l >> 4;

#pragma unroll
  for (int it = 0; it < 4; ++it) {                // gather x_t columns -> xs
    int v = it*256 + t; int cc = v >> 3; int ro = (v & 7) * 8;
    *(short8*)&sX[cc*80 + ro] = *(const short8*)(x_t + (size_t)cc*NN + r0 + ro);
  }
#pragma unroll
  for (int it = 0; it < 4; ++it) {                // stage gate rows coalesced
    int v = it*256 + t; int rr = v >> 4; int co = (v & 15) * 8;
    *(short8*)&sG[rr*132 + co] = *(const short8*)(g_in + (size_t)(r0+rr)*CD + co);
  }
  __syncthreads();                                // s1
  const int r = t >> 2, q = t & 3;
  float x[32];
#pragma unroll
  for (int i = 0; i < 32; ++i) x[i] = b2f((unsigned short)sX[(q*32+i)*80 + r]);
  float s = 0.f;
#pragma unroll
  for (int i = 0; i < 32; ++i) s += x[i];
  s += __shfl_xor(s, 1, 64);
  s += __shfl_xor(s, 2, 64);
  const float mu = s * (1.f/128.f);
  float vs = 0.f;
#pragma unroll
  for (int i = 0; i < 32; ++i) { float d = x[i]-mu; vs += d*d; }
  vs += __shfl_xor(vs, 1, 64);
  vs += __shfl_xor(vs, 2, 64);
  const float rstd = rsqrtf(vs * (1.f/128.f) + 1e-5f);
  __syncthreads();                                // s2: xs reads complete
#pragma unroll
  for (int i = 0; i < 32; ++i) {
    int c = q*32 + i;
    float y = (x[i]-mu)*rstd*ln_s[c] + ln_b[c];
    sX[r*136 + c] = (short)f2b(y);
  }
  __syncthreads();                                // s3: xln ready
  short8 af[4];
#pragma unroll
  for (int ks = 0; ks < 4; ++ks)
    af[ks] = *(const short8*)&sX[(w*16 + lr)*136 + ks*32 + lg*8];

  float4v acc[8];
#pragma unroll
  for (int cf = 0; cf < 8; ++cf) {
    float4v a = {0.f,0.f,0.f,0.f};
#pragma unroll
    for (int ks = 0; ks < 4; ++ks) {
      const float* p = w_z + (size_t)(ks*32 + lg*8)*CD + cf*16 + lr;
      short8 bf;
#pragma unroll
      for (int j = 0; j < 8; ++j) bf[j] = (short)f2b(p[(size_t)j*CD]);
      a = mfma16(af[ks], bf, a);
    }
    acc[cf] = a;
  }
  float bz[8];
#pragma unroll
  for (int cf = 0; cf < 8; ++cf) bz[cf] = b_z[cf*16 + lr];
#pragma unroll
  for (int cf = 0; cf < 8; ++cf)
#pragma unroll
    for (int jj = 0; jj < 4; ++jj) {
      int rl = w*16 + lg*4 + jj;
      float gv = b2f((unsigned short)sG[rl*132 + cf*16 + lr]);
      out[(size_t)(r0 + rl)*CD + cf*16 + lr] = (acc[cf][jj] + bz[cf]) * gv;
    }
}

extern "C" void kernel_launch(void* const* d_in, const int* in_sizes, int n_in,
                              void* d_out, int out_size, void* d_ws, size_t ws_size,
                              hipStream_t stream) {
  (void)in_sizes; (void)n_in; (void)out_size; (void)ws_size;
  const float* z     = (const float*)d_in[0];
  const float* mask  = (const float*)d_in[1];
  const float* w_a_p = (const float*)d_in[2];
  const float* b_a_p = (const float*)d_in[3];
  const float* w_a_g = (const float*)d_in[4];
  const float* b_a_g = (const float*)d_in[5];
  const float* w_b_p = (const float*)d_in[6];
  const float* b_b_p = (const float*)d_in[7];
  const float* w_b_g = (const float*)d_in[8];
  const float* b_b_g = (const float*)d_in[9];
  const float* w_g   = (const float*)d_in[10];
  const float* b_g   = (const float*)d_in[11];
  const float* w_z   = (const float*)d_in[12];
  const float* b_z   = (const float*)d_in[13];
  const float* ln_i_s = (const float*)d_in[14];
  const float* ln_i_b = (const float*)d_in[15];
  const float* ln_o_s = (const float*)d_in[16];
  const float* ln_o_b = (const float*)d_in[17];

  short* a_t = (short*)d_ws;                       // 64 MiB each, 256 MiB total
  short* b_t = a_t + (size_t)CD*NN;
  short* g_s = b_t + (size_t)CD*NN;
  short* x_t = g_s + (size_t)CD*NN;
  short* wT  = x_t;                                // 160 KB at head of x_t:
                                                   // read by kProj, overwritten later by kEinsum

  hipLaunchKernelGGL(kPrepW, dim3(64, 5), dim3(256), 0, stream,
                     w_a_p, w_a_g, w_b_p, w_b_g, w_g, wT);
  hipLaunchKernelGGL(kProj, dim3(NN/64), dim3(256), 0, stream,
                     z, mask, wT, b_a_p, b_a_g, b_b_p, b_b_g, b_g,
                     ln_i_s, ln_i_b, a_t, b_t, g_s);
  hipLaunchKernelGGL(kEinsum, dim3(2048), dim3(256), 0, stream, a_t, b_t, x_t);
  hipLaunchKernelGGL(kOut, dim3(NN/64), dim3(256), 0, stream,
                     x_t, g_s, w_z, b_z, ln_o_s, ln_o_b, (float*)d_out);
}

// Round 3
// 366.025 us; speedup vs baseline: 2.9392x; 1.5355x over previous
//
#include <hip/hip_runtime.h>

typedef __attribute__((ext_vector_type(8))) short short8;
typedef __attribute__((ext_vector_type(4))) short short4v;
typedef __attribute__((ext_vector_type(4))) float float4v;
typedef __attribute__((ext_vector_type(2))) unsigned int uint2v;

#define NDIM 512
#define NN (NDIM*NDIM)
#define CD 128

__device__ __forceinline__ unsigned short f2b(float f) {
  union { float f; unsigned u; } v; v.f = f;
  unsigned r = v.u + 0x7FFFu + ((v.u >> 16) & 1u);
  return (unsigned short)(r >> 16);
}
__device__ __forceinline__ float b2f(unsigned short h) {
  union { unsigned u; float f; } v; v.u = ((unsigned)h) << 16; return v.f;
}
__device__ __forceinline__ float sigmoidf_(float x) { return 1.f / (1.f + __expf(-x)); }
__device__ __forceinline__ unsigned pk2(float a, float b) {
  return (unsigned)f2b(a) | ((unsigned)f2b(b) << 16);
}
__device__ __forceinline__ float4v mfma16(short8 a, short8 b, float4v c) {
  return __builtin_amdgcn_mfma_f32_16x16x32_bf16(a, b, c, 0, 0, 0);
}
__device__ __forceinline__ void gl_lds16(const short* g, short* l) {
  __builtin_amdgcn_global_load_lds(
      (const __attribute__((address_space(1))) unsigned int*)g,
      (__attribute__((address_space(3))) unsigned int*)l, 16, 0, 0);
}

// fragment read from a swizzled 128-short-row LDS buffer: logical (row, 16B-chunk j)
__device__ __forceinline__ short8 fragr(const short* buf, int row, int j) {
  return *(const short8*)(buf + row * 128 + ((j ^ (row & 15)) << 3));
}

// stage one 128x128 bf16 weight [n][k] from global (pre-transposed) into swizzled LDS
__device__ __forceinline__ void stageW(const short* wslot, short* sW, int t) {
#pragma unroll
  for (int i = 0; i < 8; ++i) {
    int U = i * 256 + t;
    int row = U >> 4, u = U & 15;
    gl_lds16(wslot + row * 128 + ((u ^ (row & 15)) << 3), sW + U * 8);
  }
}

// ---------------- kernel 0: weight prep f32 [k][n] -> bf16 [n][k] ----------------
__global__ __launch_bounds__(256) void kPrepW(
    const float* __restrict__ w0, const float* __restrict__ w1,
    const float* __restrict__ w2, const float* __restrict__ w3,
    const float* __restrict__ w4, short* __restrict__ wt)
{
  const int wi = blockIdx.y;
  const float* W = wi==0 ? w0 : wi==1 ? w1 : wi==2 ? w2 : wi==3 ? w3 : w4;
  const int e = blockIdx.x * 256 + threadIdx.x;   // 0..16383
  const int k = e >> 7, n = e & 127;              // coalesced read along n
  wt[wi * 16384 + n * 128 + k] = (short)f2b(W[k * CD + n]);
}

// ---------------- kernel 1: LN(z) + 5 projections + gating ----------------
// 2048 blocks x 256 thr; block = 128 rows; wave = 32 rows (2 rowgroups)
__global__ __launch_bounds__(256, 2) void kProj(
    const float* __restrict__ z, const float* __restrict__ mask,
    const short* __restrict__ wT,
    const float* __restrict__ b_a_p, const float* __restrict__ b_a_g,
    const float* __restrict__ b_b_p, const float* __restrict__ b_b_g,
    const float* __restrict__ b_g,
    const float* __restrict__ ln_s, const float* __restrict__ ln_b,
    short* __restrict__ a_t, short* __restrict__ b_t, short* __restrict__ g_out)
{
  __shared__ short zln[128 * 128];   // swizzled
  __shared__ short sW[128 * 128];    // swizzled, single-buffered weight
  const int t = threadIdx.x;
  const int r0 = blockIdx.x * 128;
  const int w = t >> 6, l = t & 63, lr = l & 15, lg = l >> 4;

  stageW(wT + 1 * 16384, sW, t);                  // w_a_g first

  // ---- LN of 128 rows, 2 rounds, 4 threads/row ----
#pragma unroll
  for (int h = 0; h < 2; ++h) {
    const int row = h * 64 + (t >> 2), q = t & 3;
    const float* zp = z + (size_t)(r0 + row) * CD + q * 32;
    float x[32];
#pragma unroll
    for (int i = 0; i < 8; ++i) {
      float4v v = *(const float4v*)(zp + i * 4);
#pragma unroll
      for (int e = 0; e < 4; ++e) x[i*4+e] = v[e];
    }
    float s = 0.f;
#pragma unroll
    for (int i = 0; i < 32; ++i) s += x[i];
    s += __shfl_xor(s, 1, 64);
    s += __shfl_xor(s, 2, 64);
    const float mu = s * (1.f/128.f);
    float vs = 0.f;
#pragma unroll
    for (int i = 0; i < 32; ++i) { float d = x[i]-mu; vs += d*d; }
    vs += __shfl_xor(vs, 1, 64);
    vs += __shfl_xor(vs, 2, 64);
    const float rstd = rsqrtf(vs * (1.f/128.f) + 1e-5f);
#pragma unroll
    for (int i = 0; i < 32; ++i) {
      int c = q*32 + i;
      float y = (x[i]-mu)*rstd*ln_s[c] + ln_b[c];
      zln[row*128 + (((c>>3) ^ (row & 15)) << 3) + (c & 7)] = (short)f2b(y);
    }
  }

  // biases + mask (hide latency before barrier)
  float bga[8], bpa[8], bgb[8], bpb[8];
#pragma unroll
  for (int cf = 0; cf < 8; ++cf) {
    bga[cf] = b_a_g[cf*16+lr]; bpa[cf] = b_a_p[cf*16+lr];
    bgb[cf] = b_b_g[cf*16+lr]; bpb[cf] = b_b_p[cf*16+lr];
  }
  float mrow[2][4];
#pragma unroll
  for (int g = 0; g < 2; ++g)
#pragma unroll
    for (int jj = 0; jj < 4; ++jj)
      mrow[g][jj] = mask[r0 + w*32 + g*16 + lg*4 + jj];

  __syncthreads();                                // B1: zln + sW(w_a_g)

  short8 af[2][4];
#pragma unroll
  for (int g = 0; g < 2; ++g)
#pragma unroll
    for (int ks = 0; ks < 4; ++ks)
      af[g][ks] = fragr(zln, w*32 + g*16 + lr, ks*4 + lg);

  float4v accA[2][8], accB[2][8];
  float sg[2][8][4];

#define ZERO_ACC(A) do { _Pragma("unroll") for (int g_=0;g_<2;++g_) \
  _Pragma("unroll") for (int c_=0;c_<8;++c_) A[g_][c_] = (float4v){0.f,0.f,0.f,0.f}; } while(0)

  // pass: acc[g][cf] += af[g][ks] x sW-frag  (unswapped: D = (rows, c))
#define WPASS(A) do { ZERO_ACC(A);                                         \
  _Pragma("unroll") for (int ks_=0; ks_<4; ++ks_)                          \
    _Pragma("unroll") for (int cf_=0; cf_<8; ++cf_) {                      \
      short8 wf_ = fragr(sW, cf_*16 + lr, ks_*4 + lg);                     \
      _Pragma("unroll") for (int g_=0; g_<2; ++g_)                         \
        A[g_][cf_] = mfma16(af[g_][ks_], wf_, A[g_][cf_]);                 \
    } } while(0)

#define SIGPASS(BG) do { _Pragma("unroll") for (int g_=0;g_<2;++g_)        \
  _Pragma("unroll") for (int cf_=0;cf_<8;++cf_)                            \
    _Pragma("unroll") for (int j_=0;j_<4;++j_)                             \
      sg[g_][cf_][j_] = sigmoidf_(accA[g_][cf_][j_] + BG[cf_]) * mrow[g_][j_]; } while(0)

  // packed 8B store of (sg * (accB + bias)) to DST[c][rows]
#define STORE_AB(DST, BP) do { _Pragma("unroll") for (int g_=0;g_<2;++g_)  \
  _Pragma("unroll") for (int cf_=0;cf_<8;++cf_) {                          \
    float v0_ = sg[g_][cf_][0] * (accB[g_][cf_][0] + BP[cf_]);             \
    float v1_ = sg[g_][cf_][1] * (accB[g_][cf_][1] + BP[cf_]);             \
    float v2_ = sg[g_][cf_][2] * (accB[g_][cf_][2] + BP[cf_]);             \
    float v3_ = sg[g_][cf_][3] * (accB[g_][cf_][3] + BP[cf_]);             \
    uint2v pv_ = { pk2(v0_, v1_), pk2(v2_, v3_) };                         \
    *(uint2v*)(DST + (size_t)(cf_*16+lr)*NN + r0 + w*32 + g_*16 + lg*4) = pv_; \
  } } while(0)

  WPASS(accA);                                    // a_g
  SIGPASS(bga);
  __syncthreads();                                // B2: sW reads done
  stageW(wT + 0 * 16384, sW, t);                  // w_a_p
  __syncthreads();                                // B3
  WPASS(accB);                                    // a_p
  __syncthreads();                                // B4
  stageW(wT + 3 * 16384, sW, t);                  // w_b_g
  STORE_AB(a_t, bpa);                             // overlaps the stage
  __syncthreads();                                // B5
  WPASS(accA);                                    // b_g
  SIGPASS(bgb);
  __syncthreads();                                // B6
  stageW(wT + 2 * 16384, sW, t);                  // w_b_p
  __syncthreads();                                // B7
  WPASS(accB);                                    // b_p
  __syncthreads();                                // B8
  stageW(wT + 4 * 16384, sW, t);                  // w_g
  STORE_AB(b_t, bpb);
  __syncthreads();                                // B9
  // gate pass, swapped operands: D = (c, rows) -> row-major 8B stores
  {
    float4v accG[2][8];
    ZERO_ACC(accG);
#pragma unroll
    for (int ks = 0; ks < 4; ++ks)
#pragma unroll
      for (int cf = 0; cf < 8; ++cf) {
        short8 wf = fragr(sW, cf*16 + lr, ks*4 + lg);
#pragma unroll
        for (int g = 0; g < 2; ++g)
          accG[g][cf] = mfma16(wf, af[g][ks], accG[g][cf]);
      }
#pragma unroll
    for (int g = 0; g < 2; ++g)
#pragma unroll
      for (int cf = 0; cf < 8; ++cf) {
        float4v bgv = *(const float4v*)(b_g + cf*16 + lg*4);
        float v0 = sigmoidf_(accG[g][cf][0] + bgv[0]);
        float v1 = sigmoidf_(accG[g][cf][1] + bgv[1]);
        float v2 = sigmoidf_(accG[g][cf][2] + bgv[2]);
        float v3 = sigmoidf_(accG[g][cf][3] + bgv[3]);
        uint2v pv = { pk2(v0, v1), pk2(v2, v3) };
        *(uint2v*)(g_out + (size_t)(r0 + w*32 + g*16 + lr)*CD + cf*16 + lg*4) = pv;
      }
  }
}

// ---------------- kernel 2: per-channel einsum GEMM X_c = A_c * B_c^T ----------------
// BK=64, double-buffered, 2-phase pipeline
__global__ __launch_bounds__(256, 2) void kEinsum(const short* __restrict__ a_t,
                                                  const short* __restrict__ b_t,
                                                  short* __restrict__ x_t)
{
  __shared__ short As[2][128 * 64];
  __shared__ short Bs[2][128 * 64];
  const int t = threadIdx.x;
  const int d = blockIdx.x;
  const int c = (d & 7) * 16 + (d >> 7);          // channel -> XCD grouping
  const int tile = (d >> 3) & 15;
  const int i0 = (tile >> 2) * 128;
  const int j0 = (tile & 3) * 128;
  const size_t abase = (size_t)c * NN;
  const int w = t >> 6, l = t & 63, lr = l & 15, lg = l >> 4;
  const int wr = w >> 1, wc = w & 1;

  // staging source addresses (pre-swizzled global chunks, linear LDS dest)
  const short* gA[4]; const short* gB[4]; int ldsU[4];
#pragma unroll
  for (int q = 0; q < 4; ++q) {
    int U = q * 256 + t;                          // 16B-unit index, 0..1023
    int row = U >> 3, u = U & 7;
    int swz = ((u ^ (row & 7)) << 3);
    gA[q] = a_t + abase + (size_t)(i0 + row) * NDIM + swz;
    gB[q] = b_t + abase + (size_t)(j0 + row) * NDIM + swz;
    ldsU[q] = U * 8;
  }

#define STAGE_E(buf, k0) do { _Pragma("unroll") for (int q_=0;q_<4;++q_) { \
    gl_lds16(gA[q_] + (k0), &As[buf][ldsU[q_]]);                           \
    gl_lds16(gB[q_] + (k0), &Bs[buf][ldsU[q_]]); } } while(0)

  float4v acc[4][4];
#pragma unroll
  for (int m = 0; m < 4; ++m)
#pragma unroll
    for (int n = 0; n < 4; ++n) acc[m][n] = (float4v){0.f,0.f,0.f,0.f};

  STAGE_E(0, 0);
  __syncthreads();                                // prologue drain
  int cur = 0;
#pragma unroll
  for (int it = 0; it < 8; ++it) {
    if (it < 7) STAGE_E(cur ^ 1, (it + 1) * 64);
    short8 afr[4][2], bfr[4][2];
#pragma unroll
    for (int m = 0; m < 4; ++m)
#pragma unroll
      for (int ks = 0; ks < 2; ++ks) {
        int row = wr*64 + m*16 + lr, j = ks*4 + lg;
        afr[m][ks] = *(const short8*)(&As[cur][row*64 + ((j ^ (row & 7)) << 3)]);
      }
#pragma unroll
    for (int n = 0; n < 4; ++n)
#pragma unroll
      for (int ks = 0; ks < 2; ++ks) {
        int row = wc*64 + n*16 + lr, j = ks*4 + lg;
        bfr[n][ks] = *(const short8*)(&Bs[cur][row*64 + ((j ^ (row & 7)) << 3)]);
      }
#pragma unroll
    for (int ks = 0; ks < 2; ++ks)
#pragma unroll
      for (int m = 0; m < 4; ++m)
#pragma unroll
        for (int n = 0; n < 4; ++n)   // swapped: D = (j, i) -> j-major stores
          acc[m][n] = mfma16(bfr[n][ks], afr[m][ks], acc[m][n]);
    __syncthreads();
    cur ^= 1;
  }
  // epilogue: lane holds 4 consecutive j (jj) of one i -> packed 8B stores
#pragma unroll
  for (int m = 0; m < 4; ++m)
#pragma unroll
    for (int n = 0; n < 4; ++n) {
      int i  = i0 + wr*64 + m*16 + lr;
      int jb = j0 + wc*64 + n*16 + lg*4;
      uint2v pv = { pk2(acc[m][n][0], acc[m][n][1]), pk2(acc[m][n][2], acc[m][n][3]) };
      *(uint2v*)(x_t + abase + (size_t)i * NDIM + jb) = pv;
    }
}

// ---------------- kernel 3: LN(x) + x@w_z + b_z, * gate ----------------
__global__ __launch_bounds__(256, 2) void kOut(
    const short* __restrict__ x_t, const short* __restrict__ g_in,
    const float* __restrict__ w_z, const float* __restrict__ b_z,
    const float* __restrict__ ln_s, const float* __restrict__ ln_b,
    float* __restrict__ out)
{
  __shared__ short xs[128 * 72];    // gathered x [c][r], swizzled r-chunks
  __shared__ short xln[64 * 128];   // swizzled
  __shared__ short sW[128 * 128];   // swizzled w_z
  const int t = threadIdx.x;
  const int r0 = blockIdx.x * 64;
  const int w = t >> 6, l = t & 63, lr = l & 15, lg = l >> 4;

  // A) stage w_z f32 [k][n] -> swizzled bf16 [n][k] (coalesced reads, one-time)
#pragma unroll
  for (int i = 0; i < 8; ++i) {
    int flat = i * 256 + t;                       // k-pair unit
    int kp = flat >> 5, k = kp * 2, n4 = (flat & 31) * 4;
    float4v va = *(const float4v*)(w_z + (size_t)k * CD + n4);
    float4v vb = *(const float4v*)(w_z + (size_t)(k + 1) * CD + n4);
#pragma unroll
    for (int j = 0; j < 4; ++j) {
      int row = n4 + j;
      int addr = row * 128 + (((k >> 3) ^ (row & 15)) << 3) + (k & 7);
      *(unsigned*)(&sW[addr]) = pk2(va[j], vb[j]);
    }
  }
  // B) gather x columns -> xs (swizzled 16B chunks)
#pragma unroll
  for (int it = 0; it < 4; ++it) {
    int v = it * 256 + t; int cc = v >> 3; int u = v & 7;
    int up = u ^ ((cc >> 3) & 7);
    *(short8*)&xs[cc * 72 + up * 8] = *(const short8*)(x_t + (size_t)cc * NN + r0 + u * 8);
  }
  __syncthreads();                                // s1
  // C) LN over channels
  {
    const int r = t >> 2, q = t & 3;
    float x[32];
#pragma unroll
    for (int i = 0; i < 32; ++i) {
      int c = q * 32 + i;
      x[i] = b2f((unsigned short)xs[c * 72 + (((r >> 3) ^ ((c >> 3) & 7)) << 3) + (r & 7)]);
    }
    float s = 0.f;
#pragma unroll
    for (int i = 0; i < 32; ++i) s += x[i];
    s += __shfl_xor(s, 1, 64);
    s += __shfl_xor(s, 2, 64);
    const float mu = s * (1.f/128.f);
    float vs = 0.f;
#pragma unroll
    for (int i = 0; i < 32; ++i) { float d = x[i]-mu; vs += d*d; }
    vs += __shfl_xor(vs, 1, 64);
    vs += __shfl_xor(vs, 2, 64);
    const float rstd = rsqrtf(vs * (1.f/128.f) + 1e-5f);
#pragma unroll
    for (int i = 0; i < 32; ++i) {
      int c = q*32 + i;
      float y = (x[i]-mu)*rstd*ln_s[c] + ln_b[c];
      xln[r*128 + (((c>>3) ^ (r & 15)) << 3) + (c & 7)] = (short)f2b(y);
    }
  }
  __syncthreads();                                // s2
  short8 af[4];
#pragma unroll
  for (int ks = 0; ks < 4; ++ks)
    af[ks] = fragr(xln, w*16 + lr, ks*4 + lg);

  // D) swapped final mfma: D = (c, rows) -> coalesced float4 out stores
  float4v acc[8];
#pragma unroll
  for (int cf = 0; cf < 8; ++cf) acc[cf] = (float4v){0.f,0.f,0.f,0.f};
#pragma unroll
  for (int ks = 0; ks < 4; ++ks)
#pragma unroll
    for (int cf = 0; cf < 8; ++cf) {
      short8 wf = fragr(sW, cf*16 + lr, ks*4 + lg);
      acc[cf] = mfma16(wf, af[ks], acc[cf]);
    }
  const int orow = r0 + w*16 + lr;
#pragma unroll
  for (int cf = 0; cf < 8; ++cf) {
    float4v bzv = *(const float4v*)(b_z + cf*16 + lg*4);
    short4v gv = *(const short4v*)(g_in + (size_t)orow * CD + cf*16 + lg*4);
    float4v o;
#pragma unroll
    for (int j = 0; j < 4; ++j)
      o[j] = (acc[cf][j] + bzv[j]) * b2f((unsigned short)gv[j]);
    *(float4v*)(out + (size_t)orow * CD + cf*16 + lg*4) = o;
  }
}

extern "C" void kernel_launch(void* const* d_in, const int* in_sizes, int n_in,
                              void* d_out, int out_size, void* d_ws, size_t ws_size,
                              hipStream_t stream) {
  (void)in_sizes; (void)n_in; (void)out_size; (void)ws_size;
  const float* z     = (const float*)d_in[0];
  const float* mask  = (const float*)d_in[1];
  const float* w_a_p = (const float*)d_in[2];
  const float* b_a_p = (const float*)d_in[3];
  const float* w_a_g = (const float*)d_in[4];
  const float* b_a_g = (const float*)d_in[5];
  const float* w_b_p = (const float*)d_in[6];
  const float* b_b_p = (const float*)d_in[7];
  const float* w_b_g = (const float*)d_in[8];
  const float* b_b_g = (const float*)d_in[9];
  const float* w_g   = (const float*)d_in[10];
  const float* b_g   = (const float*)d_in[11];
  const float* w_z   = (const float*)d_in[12];
  const float* b_z   = (const float*)d_in[13];
  const float* ln_i_s = (const float*)d_in[14];
  const float* ln_i_b = (const float*)d_in[15];
  const float* ln_o_s = (const float*)d_in[16];
  const float* ln_o_b = (const float*)d_in[17];

  short* a_t = (short*)d_ws;                       // 64 MiB each, 256 MiB total
  short* b_t = a_t + (size_t)CD*NN;
  short* g_s = b_t + (size_t)CD*NN;
  short* x_t = g_s + (size_t)CD*NN;
  short* wT  = x_t;                                // 160 KB at head of x_t (kProj only)

  hipLaunchKernelGGL(kPrepW, dim3(64, 5), dim3(256), 0, stream,
                     w_a_p, w_a_g, w_b_p, w_b_g, w_g, wT);
  hipLaunchKernelGGL(kProj, dim3(NN/128), dim3(256), 0, stream,
                     z, mask, wT, b_a_p, b_a_g, b_b_p, b_b_g, b_g,
                     ln_i_s, ln_i_b, a_t, b_t, g_s);
  hipLaunchKernelGGL(kEinsum, dim3(2048), dim3(256), 0, stream, a_t, b_t, x_t);
  hipLaunchKernelGGL(kOut, dim3(NN/64), dim3(256), 0, stream,
                     x_t, g_s, w_z, b_z, ln_o_s, ln_o_b, (float*)d_out);
}